// Round 13
// baseline (427.690 us; speedup 1.0000x reference)
//
#include <hip/hip_runtime.h>
#include <hip/hip_bf16.h>

namespace {
constexpr int cS = 16, cB = 16, cC = 256, cH = 4, cDH = 64, cHW = 293;
constexpr int cLQ = cS * cHW;      // 4688
constexpr int cLK = 128;
constexpr int cNN = cLQ * cB;      // 75008
constexpr size_t TX_OFF = 25600;         // 5120 + 16384 + 4096
constexpr size_t HX_OFF = 2122752;       // TX_OFF + 16*16*2*64*64
}

typedef unsigned short ushort_t;
typedef unsigned int uint_t;
typedef __attribute__((ext_vector_type(8))) short short8;    // 8 bf16 (4 VGPRs)
typedef __attribute__((ext_vector_type(4))) float f32x4;     // MFMA C/D frag

__device__ __forceinline__ float bf2f(ushort_t u) {
  return __uint_as_float(((uint_t)u) << 16);
}
__device__ __forceinline__ ushort_t f2bf(float f) {
  __hip_bfloat16 h = __float2bfloat16(f);
  return *(ushort_t*)&h;
}

// SWZ frag-linear activation layout for a [rows][256] matrix:
// element (r, c) -> ((r>>4)*8 + (c>>5))*512 + ((c>>3)&3)*128 + (r&15)*8 + (c&7)
__device__ __forceinline__ size_t swz(int r, int c) {
  return (((size_t)(r >> 4) * 8 + (c >> 5)) * 64 + ((c >> 3) & 3) * 16 + (r & 15)) * 8 + (c & 7);
}

// ============ merged prep: xk cvt+swz, 8 weight swizzles ============
__global__ __launch_bounds__(256) void k_prep(
    const float* __restrict__ xk, ushort_t* __restrict__ xkb,
    const float* __restrict__ wq, ushort_t* __restrict__ wqs,
    const float* __restrict__ wk, ushort_t* __restrict__ wks,
    const float* __restrict__ wv, ushort_t* __restrict__ wvs,
    const float* __restrict__ wo, ushort_t* __restrict__ wos,
    const float* __restrict__ w1, ushort_t* __restrict__ w1s,
    const float* __restrict__ w2, ushort_t* __restrict__ w2s,
    const float* __restrict__ tw, ushort_t* __restrict__ tws,
    const float* __restrict__ hw_, ushort_t* __restrict__ hws)
{
  int bid = blockIdx.x;
  if (bid < 512) {
    int i4 = bid * 256 + threadIdx.x;
    int r = i4 >> 6;
    int c0 = (i4 & 63) * 4;
    float4 v = *(const float4*)(xk + (size_t)r * 256 + c0);
    ushort_t o[4] = {f2bf(v.x), f2bf(v.y), f2bf(v.z), f2bf(v.w)};
    *(uint2*)&xkb[swz(r, c0)] = *(uint2*)o;
    return;
  }
  int rr = bid - 512;
  const float* W; ushort_t* Ws; int N; int lb;
  if      (rr < 32)  { W = wq;  Ws = wqs; N = 256;  lb = rr; }
  else if (rr < 64)  { W = wk;  Ws = wks; N = 256;  lb = rr - 32; }
  else if (rr < 96)  { W = wv;  Ws = wvs; N = 256;  lb = rr - 64; }
  else if (rr < 128) { W = wo;  Ws = wos; N = 256;  lb = rr - 96; }
  else if (rr < 256) { W = w1;  Ws = w1s; N = 1024; lb = rr - 128; }
  else if (rr < 384) { W = w2;  Ws = w2s; N = 256;  lb = rr - 256; }
  else if (rr < 388) { W = tw;  Ws = tws; N = 32;   lb = rr - 384; }
  else               { W = hw_; Ws = hws; N = 32;   lb = rr - 388; }
  int slot = lb * 256 + threadIdx.x;
  int lane = slot & 63;
  int fr   = slot >> 6;
  int NB   = N >> 4;
  int nb   = fr % NB, kc = fr / NB;
  int n    = nb * 16 + (lane & 15);
  int k0   = kc * 32 + (lane >> 4) * 8;
  ushort_t tmp[8];
  #pragma unroll
  for (int i = 0; i < 8; ++i) tmp[i] = f2bf(W[(size_t)(k0 + i) * N + n]);
  *(uint4*)&Ws[(size_t)slot * 8] = *(uint4*)tmp;
}

// ============ core GEMM: 64 rows x (4x16 cols/wave), K=256, N-split waves ============
__device__ __forceinline__ void gemm_k256(
    const ushort_t* __restrict__ A, const ushort_t* __restrict__ Ws,
    int rt0, int slot0, int NB, int lane, f32x4 c[4][4])
{
  #pragma unroll 2
  for (int kc = 0; kc < 8; ++kc) {
    short8 a[4];
    #pragma unroll
    for (int mf = 0; mf < 4; ++mf)
      a[mf] = *(const short8*)(A + (((size_t)(rt0 + mf) * 8 + kc) * 64 + lane) * 8);
    #pragma unroll
    for (int nb = 0; nb < 4; ++nb) {
      short8 b = *(const short8*)(Ws + (((size_t)kc * NB + slot0 + nb) * 64 + lane) * 8);
      #pragma unroll
      for (int mf = 0; mf < 4; ++mf)
        c[mf][nb] = __builtin_amdgcn_mfma_f32_16x16x32_bf16(a[mf], b, c[mf][nb], 0, 0, 0);
    }
  }
}

// ============ fused xq+LN1+Q-projection -> Q row-major bf16 (coalesced epi) ======
__global__ __launch_bounds__(256, 4) void k_qnp(
    const int* __restrict__ tq, const float* __restrict__ spatial,
    const float* __restrict__ temporal, const float* __restrict__ g,
    const float* __restrict__ bt, const ushort_t* __restrict__ Ws,
    const float* __restrict__ Bi, ushort_t* __restrict__ Out)
{
  __shared__ ushort_t aT[64 * 256];    // A frags, then reused as epilogue tile
  const int tid = threadIdx.x, lane = tid & 63, w = tid >> 6;
  const int rt0 = blockIdx.x * 4, row0 = blockIdx.x * 64;
  {
    int q = rt0 + w;                   // wave-uniform
    int s = q / cHW, hw = q % cHW;
    int c0 = lane * 4;
    float4 sv = *(const float4*)(spatial + (size_t)hw * cC + c0);
    float4 g4 = *(const float4*)(g + c0);
    float4 b4 = *(const float4*)(bt + c0);
    int kc = c0 >> 5, qq = (c0 >> 3) & 3, joff = c0 & 7;
    for (int rr = 0; rr < 16; ++rr) {
      int t = tq[s * cB + rr];
      float4 tv = *(const float4*)(temporal + (size_t)t * cC + c0);
      float v0 = tv.x + sv.x, v1 = tv.y + sv.y, v2 = tv.z + sv.z, v3 = tv.w + sv.w;
      float sum = v0 + v1 + v2 + v3;
      float sum2 = v0 * v0 + v1 * v1 + v2 * v2 + v3 * v3;
      #pragma unroll
      for (int off = 32; off >= 1; off >>= 1) {
        sum  += __shfl_xor(sum,  off, 64);
        sum2 += __shfl_xor(sum2, off, 64);
      }
      float mean = sum * (1.0f / cC);
      float var  = sum2 * (1.0f / cC) - mean * mean;
      float inv  = rsqrtf(var + 1e-5f);
      ushort_t o[4] = {f2bf((v0 - mean) * inv * g4.x + b4.x),
                       f2bf((v1 - mean) * inv * g4.y + b4.y),
                       f2bf((v2 - mean) * inv * g4.z + b4.z),
                       f2bf((v3 - mean) * inv * g4.w + b4.w)};
      *(uint2*)&aT[(((w * 8 + kc) * 64) + qq * 16 + rr) * 8 + joff] = *(uint2*)o;
    }
  }
  __syncthreads();
  f32x4 z = {0.f, 0.f, 0.f, 0.f};
  f32x4 c[4][4];
  #pragma unroll
  for (int mf = 0; mf < 4; ++mf)
    #pragma unroll
    for (int nb = 0; nb < 4; ++nb) c[mf][nb] = z;
  gemm_k256(aT, Ws, 0, w * 4, 16, lane, c);
  const int lane15 = lane & 15, kq = lane >> 4;
  __syncthreads();                     // all aT frag reads complete
  #pragma unroll
  for (int nb = 0; nb < 4; ++nb) {
    int col = w * 64 + nb * 16 + lane15;
    float bias = Bi[col];
    #pragma unroll
    for (int mf = 0; mf < 4; ++mf)
      #pragma unroll
      for (int i = 0; i < 4; ++i)
        aT[(mf * 16 + kq * 4 + i) * 256 + col] = f2bf(c[mf][nb][i] + bias);
  }
  __syncthreads();
  uint2* outp = (uint2*)(Out + (size_t)row0 * 256);
  #pragma unroll
  for (int it = 0; it < 16; ++it) {
    int f = tid + it * 256;
    int row = f >> 6, c0 = (f & 63) * 4;
    outp[f] = *(uint2*)&aT[row * 256 + c0];
  }
}

// ============ K/V projections ============
__global__ __launch_bounds__(256, 4) void k_kv(
    const ushort_t* __restrict__ xkb, const ushort_t* __restrict__ wks,
    const ushort_t* __restrict__ wvs, const float* __restrict__ bk,
    const float* __restrict__ bv, ushort_t* __restrict__ Kb,
    ushort_t* __restrict__ Vb)
{
  const ushort_t* Ws = blockIdx.y ? wvs : wks;
  const float* Bi = blockIdx.y ? bv : bk;
  ushort_t* Out = blockIdx.y ? Vb : Kb;
  const int lane = threadIdx.x & 63, w = threadIdx.x >> 6;
  const int rt0 = blockIdx.x * 4, row0 = blockIdx.x * 64;
  f32x4 z = {0.f, 0.f, 0.f, 0.f};
  f32x4 c[4][4];
  #pragma unroll
  for (int mf = 0; mf < 4; ++mf)
    #pragma unroll
    for (int nb = 0; nb < 4; ++nb) c[mf][nb] = z;
  gemm_k256(xkb, Ws, rt0, w * 4, 16, lane, c);
  const int lane15 = lane & 15, kq = lane >> 4;
  #pragma unroll
  for (int nb = 0; nb < 4; ++nb) {
    int col = w * 64 + nb * 16 + lane15;
    float bias = Bi[col];
    #pragma unroll
    for (int mf = 0; mf < 4; ++mf)
      #pragma unroll
      for (int i = 0; i < 4; ++i) {
        int row = row0 + mf * 16 + kq * 4 + i;
        Out[(size_t)row * 256 + col] = f2bf(c[mf][nb][i] + bias);
      }
  }
}

// ============ MEGA-FUSED: wo + xq resid + LN2 + FFN + resid + table/hand heads ====
// 512 threads, 8 waves; wave w owns cols [w*32, w*32+32) for the GEMM phases.
// After the x2 epilogue, waves 0-3 run the table/hand head GEMM from the aT tile.
__global__ __launch_bounds__(512, 4) void k_woffn(
    const ushort_t* __restrict__ A, const ushort_t* __restrict__ wos,
    const float* __restrict__ bo, const int* __restrict__ tq,
    const float* __restrict__ spatial, const float* __restrict__ temporal,
    const float* __restrict__ g, const float* __restrict__ bt,
    const ushort_t* __restrict__ w1s, const float* __restrict__ b1,
    const ushort_t* __restrict__ w2s, const float* __restrict__ b2,
    const ushort_t* __restrict__ tws, const float* __restrict__ tb,
    const ushort_t* __restrict__ hws, const float* __restrict__ hb,
    ushort_t* xres, ushort_t* __restrict__ x2out, float* __restrict__ hout)
{
  __shared__ ushort_t aT[64 * 256];     // xln frag tile, later x2 row tile
  __shared__ ushort_t hL[64 * 256];     // x row tile (ph.3), then h frag tile
  __shared__ float red[8][64][2];       // per-wave LN2 partials
  __shared__ float meanL[64], invL[64];
  const int tid = threadIdx.x, lane = tid & 63, w = tid >> 6;   // w in [0,8)
  const int lane15 = lane & 15, kq = lane >> 4;
  const int rt0 = blockIdx.x * 4, row0 = blockIdx.x * 64;
  const f32x4 z = {0.f, 0.f, 0.f, 0.f};

  // ---- Phase 1: wo GEMM, c[4][2] over wave's 32 cols
  f32x4 c[4][2];
  #pragma unroll
  for (int mf = 0; mf < 4; ++mf)
    #pragma unroll
    for (int nb = 0; nb < 2; ++nb) c[mf][nb] = z;
  #pragma unroll 1
  for (int kc = 0; kc < 8; ++kc) {
    short8 a[4];
    #pragma unroll
    for (int mf = 0; mf < 4; ++mf)
      a[mf] = *(const short8*)(A + (((size_t)(rt0 + mf) * 8 + kc) * 64 + lane) * 8);
    #pragma unroll
    for (int nb = 0; nb < 2; ++nb) {
      short8 b = *(const short8*)(wos + (((size_t)kc * 16 + w * 2 + nb) * 64 + lane) * 8);
      #pragma unroll
      for (int mf = 0; mf < 4; ++mf)
        c[mf][nb] = __builtin_amdgcn_mfma_f32_16x16x32_bf16(a[mf], b, c[mf][nb], 0, 0, 0);
    }
  }
  // ---- + bias + xq (recomputed)
  {
    int tt[4][4], hws_[4];
    #pragma unroll
    for (int mf = 0; mf < 4; ++mf) {
      int q = rt0 + mf;
      int s = q / cHW;
      hws_[mf] = q % cHW;
      #pragma unroll
      for (int i = 0; i < 4; ++i) tt[mf][i] = tq[s * cB + kq * 4 + i];
    }
    #pragma unroll
    for (int nb = 0; nb < 2; ++nb) {
      int col = w * 32 + nb * 16 + lane15;
      float bias = bo[col];
      #pragma unroll
      for (int mf = 0; mf < 4; ++mf) {
        float sp = spatial[(size_t)hws_[mf] * cC + col];
        #pragma unroll
        for (int i = 0; i < 4; ++i)
          c[mf][nb][i] += bias + temporal[(size_t)tt[mf][i] * cC + col] + sp;
      }
    }
  }
  // ---- Phase 2: LN2 stats (cross-wave)
  #pragma unroll
  for (int mf = 0; mf < 4; ++mf)
    #pragma unroll
    for (int i = 0; i < 4; ++i) {
      float s4 = c[mf][0][i] + c[mf][1][i];
      float q4 = c[mf][0][i] * c[mf][0][i] + c[mf][1][i] * c[mf][1][i];
      #pragma unroll
      for (int off = 8; off >= 1; off >>= 1) {
        s4 += __shfl_xor(s4, off, 64);
        q4 += __shfl_xor(q4, off, 64);
      }
      if (lane15 == 0) {
        red[w][mf * 16 + kq * 4 + i][0] = s4;
        red[w][mf * 16 + kq * 4 + i][1] = q4;
      }
    }
  __syncthreads();
  if (tid < 64) {
    float S = 0.f, Q = 0.f;
    #pragma unroll
    for (int ww = 0; ww < 8; ++ww) { S += red[ww][tid][0]; Q += red[ww][tid][1]; }
    float m = S * (1.0f / cC);
    float v = Q * (1.0f / cC) - m * m;
    meanL[tid] = m;
    invL[tid] = rsqrtf(v + 1e-5f);
  }
  __syncthreads();
  // ---- Phase 3: xln -> aT frag layout; x rows -> hL row-major tile
  #pragma unroll
  for (int nb = 0; nb < 2; ++nb) {
    int col = w * 32 + nb * 16 + lane15;
    float gc = g[col], bc = bt[col];
    int qd = nb * 2 + (lane15 >> 3);   // (col&31)>>3
    int jd = lane15 & 7;
    #pragma unroll
    for (int mf = 0; mf < 4; ++mf)
      #pragma unroll
      for (int i = 0; i < 4; ++i) {
        int rl = mf * 16 + kq * 4 + i;
        float val = c[mf][nb][i];
        float lv = (val - meanL[rl]) * invL[rl] * gc + bc;
        aT[((mf * 8 + w) * 64 + qd * 16 + kq * 4 + i) * 8 + jd] = f2bf(lv);
        hL[rl * 256 + col] = f2bf(val);
      }
  }
  __syncthreads();
  // ---- stash x to global (coalesced); re-read in epilogue by a DIFFERENT thread
  {
    uint2* xw = (uint2*)(xres + (size_t)row0 * 256);
    #pragma unroll
    for (int it = 0; it < 8; ++it) {
      int f = tid + it * 512;
      int row = f >> 6, c0 = (f & 63) * 4;
      xw[f] = *(uint2*)&hL[row * 256 + c0];
    }
  }
  // ---- Phase 4: FFN loop (4 chunks of 256 h-cols; FFN1 in 2 half passes)
  f32x4 c2[4][2];
  #pragma unroll
  for (int mf = 0; mf < 4; ++mf)
    #pragma unroll
    for (int nb = 0; nb < 2; ++nb) c2[mf][nb] = z;
  for (int hc = 0; hc < 4; ++hc) {
    #pragma unroll
    for (int half = 0; half < 2; ++half) {
      f32x4 c1[4];
      #pragma unroll
      for (int mf = 0; mf < 4; ++mf) c1[mf] = z;
      #pragma unroll 1
      for (int kc = 0; kc < 8; ++kc) {
        short8 a[4];
        #pragma unroll
        for (int mf = 0; mf < 4; ++mf)
          a[mf] = *(const short8*)&aT[((mf * 8 + kc) * 64 + lane) * 8];
        int slot = hc * 16 + w * 2 + half;
        short8 b = *(const short8*)(w1s + (((size_t)kc * 64 + slot) * 64 + lane) * 8);
        #pragma unroll
        for (int mf = 0; mf < 4; ++mf)
          c1[mf] = __builtin_amdgcn_mfma_f32_16x16x32_bf16(a[mf], b, c1[mf], 0, 0, 0);
      }
      if (half == 0) __syncthreads();   // prior FFN2's hL reads complete
      // GELU = x * sigmoid(2u) = x / (1 + e^(-2u))  [exact identity]
      {
        int k2l = w * 32 + half * 16 + lane15;
        float bias = b1[hc * 256 + k2l];
        int kc2l = k2l >> 5, kq2 = (k2l >> 3) & 3, j2 = k2l & 7;
        #pragma unroll
        for (int mf = 0; mf < 4; ++mf)
          #pragma unroll
          for (int i = 0; i < 4; ++i) {
            float xx = c1[mf][i] + bias;
            float x2v = xx * xx;
            float mm = fmaf(x2v, 0.044715f, 1.0f);
            float u2 = xx * mm * -1.5957691216057308f;   // -2*sqrt(2/pi)
            float e = __expf(u2);
            float ge = xx * __builtin_amdgcn_rcpf(1.0f + e);
            hL[(((kc2l * 4 + mf) * 64) + kq2 * 16 + kq * 4 + i) * 8 + j2] = f2bf(ge);
          }
      }
    }
    __syncthreads();
    #pragma unroll 1
    for (int kc2 = 0; kc2 < 8; ++kc2) {
      short8 a2[4];
      #pragma unroll
      for (int mf = 0; mf < 4; ++mf)
        a2[mf] = *(const short8*)&hL[((kc2 * 4 + mf) * 64 + lane) * 8];
      #pragma unroll
      for (int nb = 0; nb < 2; ++nb) {
        short8 b = *(const short8*)(w2s +
            (((size_t)(hc * 8 + kc2) * 16 + w * 2 + nb) * 64 + lane) * 8);
        #pragma unroll
        for (int mf = 0; mf < 4; ++mf)
          c2[mf][nb] = __builtin_amdgcn_mfma_f32_16x16x32_bf16(a2[mf], b, c2[mf][nb], 0, 0, 0);
      }
    }
  }
  __syncthreads();                     // all aT/hL frag reads complete
  // ---- Phase 5: c2 + b2 -> aT row-major
  #pragma unroll
  for (int nb = 0; nb < 2; ++nb) {
    int col = w * 32 + nb * 16 + lane15;
    float bias = b2[col];
    #pragma unroll
    for (int mf = 0; mf < 4; ++mf)
      #pragma unroll
      for (int i = 0; i < 4; ++i)
        aT[(mf * 16 + kq * 4 + i) * 256 + col] = f2bf(c2[mf][nb][i] + bias);
  }
  __syncthreads();
  // ---- copy-out with residual; write final x2 back into aT for the head GEMM
  {
    const int rt = (tid + 256) & 511;  // different wave than the stash writer
    uint2* xp = (uint2*)(x2out + (size_t)row0 * 256);
    const uint2* xr = (const uint2*)(xres + (size_t)row0 * 256);
    #pragma unroll
    for (int it = 0; it < 8; ++it) {
      int f = rt + it * 512;
      int row = f >> 6, c0 = (f & 63) * 4;
      uint2 hv = *(uint2*)&aT[row * 256 + c0];
      uint2 rv = xr[f];
      const ushort_t* hp = (const ushort_t*)&hv;
      const ushort_t* rp = (const ushort_t*)&rv;
      ushort_t o[4];
      #pragma unroll
      for (int j = 0; j < 4; ++j) o[j] = f2bf(bf2f(hp[j]) + bf2f(rp[j]));
      xp[f] = *(uint2*)o;
      *(uint2*)&aT[row * 256 + c0] = *(uint2*)o;
    }
  }
  __syncthreads();
  // ---- fused table/hand heads: waves 0-3, 16 rows each, both heads
  if (w < 4) {
    f32x4 ct[2], ch[2];
    ct[0] = ct[1] = ch[0] = ch[1] = z;
    const ushort_t* arow = aT + (w * 16 + lane15) * 256 + kq * 8;
    #pragma unroll
    for (int kc = 0; kc < 8; ++kc) {
      short8 a = *(const short8*)(arow + kc * 32);
      #pragma unroll
      for (int nb = 0; nb < 2; ++nb) {
        short8 bt_ = *(const short8*)(tws + (((size_t)(kc * 2 + nb)) * 64 + lane) * 8);
        short8 bh_ = *(const short8*)(hws + (((size_t)(kc * 2 + nb)) * 64 + lane) * 8);
        ct[nb] = __builtin_amdgcn_mfma_f32_16x16x32_bf16(a, bt_, ct[nb], 0, 0, 0);
        ch[nb] = __builtin_amdgcn_mfma_f32_16x16x32_bf16(a, bh_, ch[nb], 0, 0, 0);
      }
    }
    #pragma unroll
    for (int nb = 0; nb < 2; ++nb) {
      int j = nb * 16 + lane15;
      float tbias = tb[j], hbias = hb[j];
      int uh = j >> 3, uw = (j >> 1) & 3, uc = j & 1;
      #pragma unroll
      for (int i = 0; i < 4; ++i) {
        int rg = row0 + w * 16 + kq * 4 + i;
        int b = rg & 15, q = rg >> 4;
        int s = (q * 3579) >> 20;          // exact q/293 for q<14768
        int hw = q - s * cHW;
        if (hw < 256) {
          int th = hw >> 4, twi = hw & 15;
          size_t idx = TX_OFF +
              ((((size_t)(s * cB + b)) * 2 + uc) * 64 + (th * 4 + uh)) * 64 + (twi * 4 + uw);
          hout[idx] = ct[nb][i] + tbias;
        } else if (hw < 292) {
          int h2 = hw - 256;
          int hh = h2 / 6, ww = h2 % 6;
          size_t idx = HX_OFF +
              ((((size_t)(s * cB + b)) * 2 + uc) * 24 + (hh * 4 + uh)) * 24 + (ww * 4 + uw);
          hout[idx] = ch[nb][i] + hbias;
        }
      }
    }
  }
}

// ============ MFMA attention: 512 threads, per (b,h), 16 q-tiles per block ============
__global__ __launch_bounds__(512, 4) void k_attn(
    const ushort_t* __restrict__ Qb, const ushort_t* __restrict__ Kb,
    const ushort_t* __restrict__ Vb, const int* __restrict__ tq,
    const int* __restrict__ tk, const int* __restrict__ pad_q,
    const int* __restrict__ pad_k, ushort_t* __restrict__ aout)
{
  __shared__ ushort_t KL[128 * 72];     // [k][d]
  __shared__ ushort_t VtL[64 * 136];    // [d][k]
  __shared__ ushort_t pL[8][16 * 136];  // per-wave P tile
  __shared__ int tkL[128];

  const int h = blockIdx.y, b = blockIdx.z;
  const int tid = threadIdx.x, lane = tid & 63, w = tid >> 6;   // w in [0,8)
  const int m15 = lane & 15, quad = lane >> 4;

  for (int i = tid; i < 128 * 16; i += 512) {
    int k = i >> 4, d4 = (i & 15) * 4;
    size_t src = (size_t)(k * cB + b) * 256 + h * 64 + d4;
    uint2 kv = *(const uint2*)&Kb[src];
    uint2 vv = *(const uint2*)&Vb[src];
    *(uint2*)&KL[k * 72 + d4] = kv;
    const ushort_t* vvp = (const ushort_t*)&vv;
    #pragma unroll
    for (int t = 0; t < 4; ++t) VtL[(d4 + t) * 136 + k] = vvp[t];
  }
  if (tid < 128) tkL[tid] = tk[tid * cB + b];
  __syncthreads();
  const int pk = pad_k[b];
  const int pq = pad_q[b] * cHW;
  ushort_t* pRow = pL[w];
  const f32x4 z = {0.f, 0.f, 0.f, 0.f};

  for (int pr = 0; pr < 2; ++pr) {
    int qt = blockIdx.x * 16 + pr * 8 + w;
    if (qt >= 293) break;                       // wave-uniform
    const ushort_t* qrow =
        Qb + ((size_t)((qt * 16 + m15) * cB + b)) * 256 + h * 64 + quad * 8;
    short8 qa0 = *(const short8*)(qrow);
    short8 qa1 = *(const short8*)(qrow + 32);
    f32x4 s[8];
    #pragma unroll
    for (int nf = 0; nf < 8; ++nf) {
      const ushort_t* kp = KL + (nf * 16 + m15) * 72 + quad * 8;
      short8 b0 = *(const short8*)(kp);
      short8 b1 = *(const short8*)(kp + 32);
      s[nf] = __builtin_amdgcn_mfma_f32_16x16x32_bf16(qa0, b0, z, 0, 0, 0);
      s[nf] = __builtin_amdgcn_mfma_f32_16x16x32_bf16(qa1, b1, s[nf], 0, 0, 0);
    }
    int tqv[4], qok[4];
    #pragma unroll
    for (int i = 0; i < 4; ++i) {
      int qg = qt * 16 + quad * 4 + i;
      int sidx = (qg * 3579) >> 20;            // exact q/293 for q<14768
      tqv[i] = tq[sidx * cB + b];
      qok[i] = (qg < pq);
    }
    #pragma unroll
    for (int nf = 0; nf < 8; ++nf) {
      int kidx = nf * 16 + m15;
      int tkc = tkL[kidx];
      bool kok = (kidx < pk);
      #pragma unroll
      for (int i = 0; i < 4; ++i) {
        bool ok = kok && qok[i] && (tkc <= tqv[i]);
        s[nf][i] = ok ? s[nf][i] * 0.125f : -1e9f;
      }
    }
    float mx[4], l[4];
    #pragma unroll
    for (int i = 0; i < 4; ++i) {
      float m = s[0][i];
      #pragma unroll
      for (int nf = 1; nf < 8; ++nf) m = fmaxf(m, s[nf][i]);
      #pragma unroll
      for (int off = 8; off >= 1; off >>= 1) m = fmaxf(m, __shfl_xor(m, off, 64));
      mx[i] = m;
    }
    #pragma unroll
    for (int i = 0; i < 4; ++i) l[i] = 0.f;
    #pragma unroll
    for (int nf = 0; nf < 8; ++nf)
      #pragma unroll
      for (int i = 0; i < 4; ++i) {
        float p = __expf(s[nf][i] - mx[i]);
        s[nf][i] = p;
        l[i] += p;
      }
    #pragma unroll
    for (int i = 0; i < 4; ++i) {
      float t = l[i];
      #pragma unroll
      for (int off = 8; off >= 1; off >>= 1) t += __shfl_xor(t, off, 64);
      l[i] = 1.0f / t;
    }
    #pragma unroll
    for (int nf = 0; nf < 8; ++nf)
      #pragma unroll
      for (int i = 0; i < 4; ++i)
        pRow[(quad * 4 + i) * 136 + nf * 16 + m15] = f2bf(s[nf][i]);
    f32x4 o[4];
    #pragma unroll
    for (int nf = 0; nf < 4; ++nf) o[nf] = z;
    #pragma unroll
    for (int kc = 0; kc < 4; ++kc) {
      short8 pa = *(const short8*)(pRow + m15 * 136 + kc * 32 + quad * 8);
      #pragma unroll
      for (int nf = 0; nf < 4; ++nf) {
        short8 vb = *(const short8*)(VtL + (nf * 16 + m15) * 136 + kc * 32 + quad * 8);
        o[nf] = __builtin_amdgcn_mfma_f32_16x16x32_bf16(pa, vb, o[nf], 0, 0, 0);
      }
    }
    #pragma unroll
    for (int nf = 0; nf < 4; ++nf) {
      int c = h * 64 + nf * 16 + m15;
      size_t base = ((size_t)(c >> 5)) * 64 + ((c >> 3) & 3) * 16 + b;
      int cj = c & 7;
      #pragma unroll
      for (int i = 0; i < 4; ++i) {
        int qg = qt * 16 + quad * 4 + i;
        aout[(((size_t)qg * 8) * 64 + base) * 8 + cj] = f2bf(o[nf][i] * l[i]);
      }
    }
  }
}

// ============ gx heads: mode / shape / color ============
__global__ __launch_bounds__(128) void k_gx(
    const ushort_t* __restrict__ x2,
    const float* __restrict__ mw, const float* __restrict__ mbi,
    const float* __restrict__ sw, const float* __restrict__ sbi,
    const float* __restrict__ cw, const float* __restrict__ cbi,
    float* __restrict__ out)
{
  int sb = blockIdx.x;              // s*16 + b
  int s = sb >> 4, b = sb & 15;
  __shared__ float rowL[256];
  const ushort_t* row = x2 + ((size_t)(s * cHW + 292) * cB + b) * cC;
  for (int i = threadIdx.x; i < 256; i += 128) rowL[i] = bf2f(row[i]);
  __syncthreads();
  int j = threadIdx.x;
  if (j < 100) {
    const float* W;
    const float* Bi;
    int jj, M;
    size_t off;
    if (j < 20)      { W = mw; Bi = mbi; jj = j;      M = 20; off = 0;     }
    else if (j < 84) { W = sw; Bi = sbi; jj = j - 20; M = 64; off = 5120;  }
    else             { W = cw; Bi = cbi; jj = j - 84; M = 16; off = 21504; }
    float acc = Bi[jj];
    for (int c = 0; c < 256; ++c) acc = fmaf(rowL[c], W[c * M + jj], acc);
    out[off + (size_t)sb * M + jj] = acc;
  }
}

extern "C" void kernel_launch(void* const* d_in, const int* in_sizes, int n_in,
                              void* d_out, int out_size, void* d_ws, size_t ws_size,
                              hipStream_t stream)
{
  const int*   tq       = (const int*)d_in[0];
  const int*   pad_q    = (const int*)d_in[1];
  const float* xk       = (const float*)d_in[2];
  const int*   tk       = (const int*)d_in[3];
  const int*   pad_k    = (const int*)d_in[4];
  const float* spatial  = (const float*)d_in[8];
  const float* temporal = (const float*)d_in[9];
  const float* ln1_g    = (const float*)d_in[10];
  const float* ln1_b    = (const float*)d_in[11];
  const float* wq       = (const float*)d_in[12];
  const float* bq       = (const float*)d_in[13];
  const float* wk       = (const float*)d_in[14];
  const float* bk       = (const float*)d_in[15];
  const float* wv       = (const float*)d_in[16];
  const float* bv       = (const float*)d_in[17];
  const float* wo       = (const float*)d_in[18];
  const float* bo       = (const float*)d_in[19];
  const float* ln2_g    = (const float*)d_in[20];
  const float* ln2_b    = (const float*)d_in[21];
  const float* w1       = (const float*)d_in[22];
  const float* b1       = (const float*)d_in[23];
  const float* w2       = (const float*)d_in[24];
  const float* b2       = (const float*)d_in[25];
  const float* table_w  = (const float*)d_in[26];
  const float* table_b  = (const float*)d_in[27];
  const float* hand_w   = (const float*)d_in[28];
  const float* hand_b   = (const float*)d_in[29];
  const float* mode_w   = (const float*)d_in[30];
  const float* mode_b   = (const float*)d_in[31];
  const float* shape_w  = (const float*)d_in[32];
  const float* shape_b  = (const float*)d_in[33];
  const float* color_w  = (const float*)d_in[34];
  const float* color_b  = (const float*)d_in[35];
  float* out = (float*)d_out;

  char* ws = (char*)d_ws;
  const size_t NB2 = (size_t)cNN * cC * sizeof(ushort_t);      // 38,404,096
  ushort_t* buf1 = (ushort_t*)ws;                              // a_swz -> x stash
  ushort_t* buf2 = (ushort_t*)(ws + NB2);                      // Q -> x2
  char* p = ws + 2 * NB2;
  ushort_t* Kb  = (ushort_t*)p;  p += (size_t)cLK * cB * 256 * 2;
  ushort_t* Vb  = (ushort_t*)p;  p += (size_t)cLK * cB * 256 * 2;
  ushort_t* xkb = (ushort_t*)p;  p += (size_t)cLK * cB * 256 * 2;
  ushort_t* wqs = (ushort_t*)p;  p += 256 * 256 * 2;
  ushort_t* wks = (ushort_t*)p;  p += 256 * 256 * 2;
  ushort_t* wvs = (ushort_t*)p;  p += 256 * 256 * 2;
  ushort_t* wos = (ushort_t*)p;  p += 256 * 256 * 2;
  ushort_t* w1s = (ushort_t*)p;  p += 256 * 1024 * 2;
  ushort_t* w2s = (ushort_t*)p;  p += 1024 * 256 * 2;
  ushort_t* tws = (ushort_t*)p;  p += 256 * 32 * 2;
  ushort_t* hws = (ushort_t*)p;  p += 256 * 32 * 2;

  k_prep<<<904, 256, 0, stream>>>(xk, xkb, wq, wqs, wk, wks, wv, wvs,
                                  wo, wos, w1, w1s, w2, w2s,
                                  table_w, tws, hand_w, hws);
  k_kv<<<dim3(32, 2), 256, 0, stream>>>(xkb, wks, wvs, bk, bv, Kb, Vb);
  k_qnp<<<cNN / 64, 256, 0, stream>>>(tq, spatial, temporal, ln1_g, ln1_b,
                                      wqs, bq, buf2);
  k_attn<<<dim3(19, cH, cB), 512, 0, stream>>>(buf2, Kb, Vb, tq, tk,
                                               pad_q, pad_k, buf1);
  k_woffn<<<cNN / 64, 512, 0, stream>>>(buf1, wos, bo, tq, spatial, temporal,
                                        ln2_g, ln2_b, w1s, b1, w2s, b2,
                                        tws, table_b, hws, hand_b,
                                        buf1, buf2, out);
  k_gx<<<cS * cB, 128, 0, stream>>>(buf2, mode_w, mode_b, shape_w, shape_b,
                                    color_w, color_b, out);
}

// Round 14
// 412.445 us; speedup vs baseline: 1.0370x; 1.0370x over previous
//
#include <hip/hip_runtime.h>
#include <hip/hip_bf16.h>

namespace {
constexpr int cS = 16, cB = 16, cC = 256, cH = 4, cDH = 64, cHW = 293;
constexpr int cLQ = cS * cHW;      // 4688
constexpr int cLK = 128;
constexpr int cNN = cLQ * cB;      // 75008
constexpr size_t TX_OFF = 25600;         // 5120 + 16384 + 4096
constexpr size_t HX_OFF = 2122752;       // TX_OFF + 16*16*2*64*64
}

typedef unsigned short ushort_t;
typedef unsigned int uint_t;
typedef __attribute__((ext_vector_type(8))) short short8;    // 8 bf16 (4 VGPRs)
typedef __attribute__((ext_vector_type(4))) float f32x4;     // MFMA C/D frag

__device__ __forceinline__ float bf2f(ushort_t u) {
  return __uint_as_float(((uint_t)u) << 16);
}
__device__ __forceinline__ ushort_t f2bf(float f) {
  __hip_bfloat16 h = __float2bfloat16(f);
  return *(ushort_t*)&h;
}

// SWZ frag-linear activation layout for a [rows][256] matrix:
// element (r, c) -> ((r>>4)*8 + (c>>5))*512 + ((c>>3)&3)*128 + (r&15)*8 + (c&7)
__device__ __forceinline__ size_t swz(int r, int c) {
  return (((size_t)(r >> 4) * 8 + (c >> 5)) * 64 + ((c >> 3) & 3) * 16 + (r & 15)) * 8 + (c & 7);
}

// ============ merged prep: xk cvt+swz, 8 weight swizzles ============
__global__ __launch_bounds__(256) void k_prep(
    const float* __restrict__ xk, ushort_t* __restrict__ xkb,
    const float* __restrict__ wq, ushort_t* __restrict__ wqs,
    const float* __restrict__ wk, ushort_t* __restrict__ wks,
    const float* __restrict__ wv, ushort_t* __restrict__ wvs,
    const float* __restrict__ wo, ushort_t* __restrict__ wos,
    const float* __restrict__ w1, ushort_t* __restrict__ w1s,
    const float* __restrict__ w2, ushort_t* __restrict__ w2s,
    const float* __restrict__ tw, ushort_t* __restrict__ tws,
    const float* __restrict__ hw_, ushort_t* __restrict__ hws)
{
  int bid = blockIdx.x;
  if (bid < 512) {
    int i4 = bid * 256 + threadIdx.x;
    int r = i4 >> 6;
    int c0 = (i4 & 63) * 4;
    float4 v = *(const float4*)(xk + (size_t)r * 256 + c0);
    ushort_t o[4] = {f2bf(v.x), f2bf(v.y), f2bf(v.z), f2bf(v.w)};
    *(uint2*)&xkb[swz(r, c0)] = *(uint2*)o;
    return;
  }
  int rr = bid - 512;
  const float* W; ushort_t* Ws; int N; int lb;
  if      (rr < 32)  { W = wq;  Ws = wqs; N = 256;  lb = rr; }
  else if (rr < 64)  { W = wk;  Ws = wks; N = 256;  lb = rr - 32; }
  else if (rr < 96)  { W = wv;  Ws = wvs; N = 256;  lb = rr - 64; }
  else if (rr < 128) { W = wo;  Ws = wos; N = 256;  lb = rr - 96; }
  else if (rr < 256) { W = w1;  Ws = w1s; N = 1024; lb = rr - 128; }
  else if (rr < 384) { W = w2;  Ws = w2s; N = 256;  lb = rr - 256; }
  else if (rr < 388) { W = tw;  Ws = tws; N = 32;   lb = rr - 384; }
  else               { W = hw_; Ws = hws; N = 32;   lb = rr - 388; }
  int slot = lb * 256 + threadIdx.x;
  int lane = slot & 63;
  int fr   = slot >> 6;
  int NB   = N >> 4;
  int nb   = fr % NB, kc = fr / NB;
  int n    = nb * 16 + (lane & 15);
  int k0   = kc * 32 + (lane >> 4) * 8;
  ushort_t tmp[8];
  #pragma unroll
  for (int i = 0; i < 8; ++i) tmp[i] = f2bf(W[(size_t)(k0 + i) * N + n]);
  *(uint4*)&Ws[(size_t)slot * 8] = *(uint4*)tmp;
}

// ============ core GEMM: 64 rows x (4x16 cols/wave), K=256, N-split waves ============
__device__ __forceinline__ void gemm_k256(
    const ushort_t* __restrict__ A, const ushort_t* __restrict__ Ws,
    int rt0, int slot0, int NB, int lane, f32x4 c[4][4])
{
  #pragma unroll 2
  for (int kc = 0; kc < 8; ++kc) {
    short8 a[4];
    #pragma unroll
    for (int mf = 0; mf < 4; ++mf)
      a[mf] = *(const short8*)(A + (((size_t)(rt0 + mf) * 8 + kc) * 64 + lane) * 8);
    #pragma unroll
    for (int nb = 0; nb < 4; ++nb) {
      short8 b = *(const short8*)(Ws + (((size_t)kc * NB + slot0 + nb) * 64 + lane) * 8);
      #pragma unroll
      for (int mf = 0; mf < 4; ++mf)
        c[mf][nb] = __builtin_amdgcn_mfma_f32_16x16x32_bf16(a[mf], b, c[mf][nb], 0, 0, 0);
    }
  }
}

// ============ merged: fused xq+LN1+Q-projection (bid<1172) OR K/V proj (bid>=1172) ====
__global__ __launch_bounds__(256, 4) void k_qnpkv(
    const int* __restrict__ tq, const float* __restrict__ spatial,
    const float* __restrict__ temporal, const float* __restrict__ g,
    const float* __restrict__ bt, const ushort_t* __restrict__ wqs,
    const float* __restrict__ bq, ushort_t* __restrict__ Out,
    const ushort_t* __restrict__ xkb, const ushort_t* __restrict__ wks,
    const ushort_t* __restrict__ wvs, const float* __restrict__ bk,
    const float* __restrict__ bv, ushort_t* __restrict__ Kb,
    ushort_t* __restrict__ Vb)
{
  __shared__ ushort_t aT[64 * 256];    // A frags, then reused as epilogue tile
  const int NQ = cNN / 64;             // 1172
  const int tid = threadIdx.x, lane = tid & 63, w = tid >> 6;
  const int lane15 = lane & 15, kq = lane >> 4;
  f32x4 z = {0.f, 0.f, 0.f, 0.f};

  if ((int)blockIdx.x >= NQ) {
    // ---- K/V projection path
    int bid2 = blockIdx.x - NQ;        // 0..63
    const ushort_t* Ws = (bid2 >> 5) ? wvs : wks;
    const float* Bi = (bid2 >> 5) ? bv : bk;
    ushort_t* Kv = (bid2 >> 5) ? Vb : Kb;
    const int bx = bid2 & 31;
    const int rt0 = bx * 4, row0 = bx * 64;
    f32x4 c[4][4];
    #pragma unroll
    for (int mf = 0; mf < 4; ++mf)
      #pragma unroll
      for (int nb = 0; nb < 4; ++nb) c[mf][nb] = z;
    gemm_k256(xkb, Ws, rt0, w * 4, 16, lane, c);
    #pragma unroll
    for (int nb = 0; nb < 4; ++nb) {
      int col = w * 64 + nb * 16 + lane15;
      float bias = Bi[col];
      #pragma unroll
      for (int mf = 0; mf < 4; ++mf)
        #pragma unroll
        for (int i = 0; i < 4; ++i) {
          int row = row0 + mf * 16 + kq * 4 + i;
          Kv[(size_t)row * 256 + col] = f2bf(c[mf][nb][i] + bias);
        }
    }
    return;
  }

  // ---- xq + LN1 + Q-projection path
  const int rt0 = blockIdx.x * 4, row0 = blockIdx.x * 64;
  {
    int q = rt0 + w;                   // wave-uniform
    int s = q / cHW, hw = q % cHW;
    int c0 = lane * 4;
    float4 sv = *(const float4*)(spatial + (size_t)hw * cC + c0);
    float4 g4 = *(const float4*)(g + c0);
    float4 b4 = *(const float4*)(bt + c0);
    int kc = c0 >> 5, qq = (c0 >> 3) & 3, joff = c0 & 7;
    for (int rr = 0; rr < 16; ++rr) {
      int t = tq[s * cB + rr];
      float4 tv = *(const float4*)(temporal + (size_t)t * cC + c0);
      float v0 = tv.x + sv.x, v1 = tv.y + sv.y, v2 = tv.z + sv.z, v3 = tv.w + sv.w;
      float sum = v0 + v1 + v2 + v3;
      float sum2 = v0 * v0 + v1 * v1 + v2 * v2 + v3 * v3;
      #pragma unroll
      for (int off = 32; off >= 1; off >>= 1) {
        sum  += __shfl_xor(sum,  off, 64);
        sum2 += __shfl_xor(sum2, off, 64);
      }
      float mean = sum * (1.0f / cC);
      float var  = sum2 * (1.0f / cC) - mean * mean;
      float inv  = rsqrtf(var + 1e-5f);
      ushort_t o[4] = {f2bf((v0 - mean) * inv * g4.x + b4.x),
                       f2bf((v1 - mean) * inv * g4.y + b4.y),
                       f2bf((v2 - mean) * inv * g4.z + b4.z),
                       f2bf((v3 - mean) * inv * g4.w + b4.w)};
      *(uint2*)&aT[(((w * 8 + kc) * 64) + qq * 16 + rr) * 8 + joff] = *(uint2*)o;
    }
  }
  __syncthreads();
  f32x4 c[4][4];
  #pragma unroll
  for (int mf = 0; mf < 4; ++mf)
    #pragma unroll
    for (int nb = 0; nb < 4; ++nb) c[mf][nb] = z;
  gemm_k256(aT, wqs, 0, w * 4, 16, lane, c);
  __syncthreads();                     // all aT frag reads complete
  #pragma unroll
  for (int nb = 0; nb < 4; ++nb) {
    int col = w * 64 + nb * 16 + lane15;
    float bias = bq[col];
    #pragma unroll
    for (int mf = 0; mf < 4; ++mf)
      #pragma unroll
      for (int i = 0; i < 4; ++i)
        aT[(mf * 16 + kq * 4 + i) * 256 + col] = f2bf(c[mf][nb][i] + bias);
  }
  __syncthreads();
  uint2* outp = (uint2*)(Out + (size_t)row0 * 256);
  #pragma unroll
  for (int it = 0; it < 16; ++it) {
    int f = tid + it * 256;
    int row = f >> 6, c0 = (f & 63) * 4;
    outp[f] = *(uint2*)&aT[row * 256 + c0];
  }
}

// ============ MEGA-FUSED: wo proj + xq resid + LN2 + FFN1 + GELU + FFN2 + resid ====
// 512 threads, 8 waves; wave w owns cols [w*32, w*32+32).
__global__ __launch_bounds__(512, 4) void k_woffn(
    const ushort_t* __restrict__ A, const ushort_t* __restrict__ wos,
    const float* __restrict__ bo, const int* __restrict__ tq,
    const float* __restrict__ spatial, const float* __restrict__ temporal,
    const float* __restrict__ g, const float* __restrict__ bt,
    const ushort_t* __restrict__ w1s, const float* __restrict__ b1,
    const ushort_t* __restrict__ w2s, const float* __restrict__ b2,
    ushort_t* xres, ushort_t* __restrict__ x2out)
{
  __shared__ ushort_t aT[64 * 256];     // xln frag tile, later epilogue tile
  __shared__ ushort_t hL[64 * 256];     // x row tile (ph.3), then h frag tile
  __shared__ float red[8][64][2];       // per-wave LN2 partials
  __shared__ float meanL[64], invL[64];
  const int tid = threadIdx.x, lane = tid & 63, w = tid >> 6;   // w in [0,8)
  const int lane15 = lane & 15, kq = lane >> 4;
  const int rt0 = blockIdx.x * 4, row0 = blockIdx.x * 64;
  const f32x4 z = {0.f, 0.f, 0.f, 0.f};

  // ---- Phase 1: wo GEMM, c[4][2] over wave's 32 cols
  f32x4 c[4][2];
  #pragma unroll
  for (int mf = 0; mf < 4; ++mf)
    #pragma unroll
    for (int nb = 0; nb < 2; ++nb) c[mf][nb] = z;
  #pragma unroll 1
  for (int kc = 0; kc < 8; ++kc) {
    short8 a[4];
    #pragma unroll
    for (int mf = 0; mf < 4; ++mf)
      a[mf] = *(const short8*)(A + (((size_t)(rt0 + mf) * 8 + kc) * 64 + lane) * 8);
    #pragma unroll
    for (int nb = 0; nb < 2; ++nb) {
      short8 b = *(const short8*)(wos + (((size_t)kc * 16 + w * 2 + nb) * 64 + lane) * 8);
      #pragma unroll
      for (int mf = 0; mf < 4; ++mf)
        c[mf][nb] = __builtin_amdgcn_mfma_f32_16x16x32_bf16(a[mf], b, c[mf][nb], 0, 0, 0);
    }
  }
  // ---- + bias + xq (recomputed)
  {
    int tt[4][4], hws_[4];
    #pragma unroll
    for (int mf = 0; mf < 4; ++mf) {
      int q = rt0 + mf;
      int s = q / cHW;
      hws_[mf] = q % cHW;
      #pragma unroll
      for (int i = 0; i < 4; ++i) tt[mf][i] = tq[s * cB + kq * 4 + i];
    }
    #pragma unroll
    for (int nb = 0; nb < 2; ++nb) {
      int col = w * 32 + nb * 16 + lane15;
      float bias = bo[col];
      #pragma unroll
      for (int mf = 0; mf < 4; ++mf) {
        float sp = spatial[(size_t)hws_[mf] * cC + col];
        #pragma unroll
        for (int i = 0; i < 4; ++i)
          c[mf][nb][i] += bias + temporal[(size_t)tt[mf][i] * cC + col] + sp;
      }
    }
  }
  // ---- Phase 2: LN2 stats (cross-wave)
  #pragma unroll
  for (int mf = 0; mf < 4; ++mf)
    #pragma unroll
    for (int i = 0; i < 4; ++i) {
      float s4 = c[mf][0][i] + c[mf][1][i];
      float q4 = c[mf][0][i] * c[mf][0][i] + c[mf][1][i] * c[mf][1][i];
      #pragma unroll
      for (int off = 8; off >= 1; off >>= 1) {
        s4 += __shfl_xor(s4, off, 64);
        q4 += __shfl_xor(q4, off, 64);
      }
      if (lane15 == 0) {
        red[w][mf * 16 + kq * 4 + i][0] = s4;
        red[w][mf * 16 + kq * 4 + i][1] = q4;
      }
    }
  __syncthreads();
  if (tid < 64) {
    float S = 0.f, Q = 0.f;
    #pragma unroll
    for (int ww = 0; ww < 8; ++ww) { S += red[ww][tid][0]; Q += red[ww][tid][1]; }
    float m = S * (1.0f / cC);
    float v = Q * (1.0f / cC) - m * m;
    meanL[tid] = m;
    invL[tid] = rsqrtf(v + 1e-5f);
  }
  __syncthreads();
  // ---- Phase 3: xln -> aT frag layout; x rows -> hL row-major tile
  #pragma unroll
  for (int nb = 0; nb < 2; ++nb) {
    int col = w * 32 + nb * 16 + lane15;
    float gc = g[col], bc = bt[col];
    int qd = nb * 2 + (lane15 >> 3);   // (col&31)>>3
    int jd = lane15 & 7;
    #pragma unroll
    for (int mf = 0; mf < 4; ++mf)
      #pragma unroll
      for (int i = 0; i < 4; ++i) {
        int rl = mf * 16 + kq * 4 + i;
        float val = c[mf][nb][i];
        float lv = (val - meanL[rl]) * invL[rl] * gc + bc;
        aT[((mf * 8 + w) * 64 + qd * 16 + kq * 4 + i) * 8 + jd] = f2bf(lv);
        hL[rl * 256 + col] = f2bf(val);
      }
  }
  __syncthreads();
  // ---- stash x to global (coalesced); re-read in epilogue by a DIFFERENT thread
  {
    uint2* xw = (uint2*)(xres + (size_t)row0 * 256);
    #pragma unroll
    for (int it = 0; it < 8; ++it) {
      int f = tid + it * 512;
      int row = f >> 6, c0 = (f & 63) * 4;
      xw[f] = *(uint2*)&hL[row * 256 + c0];
    }
  }
  // ---- Phase 4: FFN loop (4 chunks of 256 h-cols; FFN1 in 2 half passes)
  f32x4 c2[4][2];
  #pragma unroll
  for (int mf = 0; mf < 4; ++mf)
    #pragma unroll
    for (int nb = 0; nb < 2; ++nb) c2[mf][nb] = z;
  for (int hc = 0; hc < 4; ++hc) {
    #pragma unroll
    for (int half = 0; half < 2; ++half) {
      f32x4 c1[4];
      #pragma unroll
      for (int mf = 0; mf < 4; ++mf) c1[mf] = z;
      #pragma unroll 1
      for (int kc = 0; kc < 8; ++kc) {
        short8 a[4];
        #pragma unroll
        for (int mf = 0; mf < 4; ++mf)
          a[mf] = *(const short8*)&aT[((mf * 8 + kc) * 64 + lane) * 8];
        int slot = hc * 16 + w * 2 + half;
        short8 b = *(const short8*)(w1s + (((size_t)kc * 64 + slot) * 64 + lane) * 8);
        #pragma unroll
        for (int mf = 0; mf < 4; ++mf)
          c1[mf] = __builtin_amdgcn_mfma_f32_16x16x32_bf16(a[mf], b, c1[mf], 0, 0, 0);
      }
      if (half == 0) __syncthreads();   // prior FFN2's hL reads complete
      // GELU = x * sigmoid(2u) = x / (1 + e^(-2u))  [exact identity]
      {
        int k2l = w * 32 + half * 16 + lane15;
        float bias = b1[hc * 256 + k2l];
        int kc2l = k2l >> 5, kq2 = (k2l >> 3) & 3, j2 = k2l & 7;
        #pragma unroll
        for (int mf = 0; mf < 4; ++mf)
          #pragma unroll
          for (int i = 0; i < 4; ++i) {
            float xx = c1[mf][i] + bias;
            float x2v = xx * xx;
            float mm = fmaf(x2v, 0.044715f, 1.0f);
            float u2 = xx * mm * -1.5957691216057308f;   // -2*sqrt(2/pi)
            float e = __expf(u2);
            float ge = xx * __builtin_amdgcn_rcpf(1.0f + e);
            hL[(((kc2l * 4 + mf) * 64) + kq2 * 16 + kq * 4 + i) * 8 + j2] = f2bf(ge);
          }
      }
    }
    __syncthreads();
    #pragma unroll 1
    for (int kc2 = 0; kc2 < 8; ++kc2) {
      short8 a2[4];
      #pragma unroll
      for (int mf = 0; mf < 4; ++mf)
        a2[mf] = *(const short8*)&hL[((kc2 * 4 + mf) * 64 + lane) * 8];
      #pragma unroll
      for (int nb = 0; nb < 2; ++nb) {
        short8 b = *(const short8*)(w2s +
            (((size_t)(hc * 8 + kc2) * 16 + w * 2 + nb) * 64 + lane) * 8);
        #pragma unroll
        for (int mf = 0; mf < 4; ++mf)
          c2[mf][nb] = __builtin_amdgcn_mfma_f32_16x16x32_bf16(a2[mf], b, c2[mf][nb], 0, 0, 0);
      }
    }
  }
  __syncthreads();                     // all aT/hL frag reads complete
  // ---- Phase 5: c2 + b2 -> aT row-major; then coalesced out with residual
  #pragma unroll
  for (int nb = 0; nb < 2; ++nb) {
    int col = w * 32 + nb * 16 + lane15;
    float bias = b2[col];
    #pragma unroll
    for (int mf = 0; mf < 4; ++mf)
      #pragma unroll
      for (int i = 0; i < 4; ++i)
        aT[(mf * 16 + kq * 4 + i) * 256 + col] = f2bf(c2[mf][nb][i] + bias);
  }
  __syncthreads();
  {
    // reader thread = tid+256 (mod 512) -> different wave than the stash writer
    const int rt = (tid + 256) & 511;
    uint2* xp = (uint2*)(x2out + (size_t)row0 * 256);
    const uint2* xr = (const uint2*)(xres + (size_t)row0 * 256);
    #pragma unroll
    for (int it = 0; it < 8; ++it) {
      int f = rt + it * 512;
      int row = f >> 6, c0 = (f & 63) * 4;
      uint2 hv = *(uint2*)&aT[row * 256 + c0];
      uint2 rv = xr[f];
      const ushort_t* hp = (const ushort_t*)&hv;
      const ushort_t* rp = (const ushort_t*)&rv;
      ushort_t o[4];
      #pragma unroll
      for (int j = 0; j < 4; ++j) o[j] = f2bf(bf2f(hp[j]) + bf2f(rp[j]));
      xp[f] = *(uint2*)o;
    }
  }
}

// ============ MFMA attention: 512 threads, per (b,h), 16 q-tiles per block ============
__global__ __launch_bounds__(512, 4) void k_attn(
    const ushort_t* __restrict__ Qb, const ushort_t* __restrict__ Kb,
    const ushort_t* __restrict__ Vb, const int* __restrict__ tq,
    const int* __restrict__ tk, const int* __restrict__ pad_q,
    const int* __restrict__ pad_k, ushort_t* __restrict__ aout)
{
  __shared__ ushort_t KL[128 * 72];     // [k][d]
  __shared__ ushort_t VtL[64 * 136];    // [d][k]
  __shared__ ushort_t pL[8][16 * 136];  // per-wave P tile
  __shared__ int tkL[128];

  const int h = blockIdx.y, b = blockIdx.z;
  const int tid = threadIdx.x, lane = tid & 63, w = tid >> 6;   // w in [0,8)
  const int m15 = lane & 15, quad = lane >> 4;

  for (int i = tid; i < 128 * 16; i += 512) {
    int k = i >> 4, d4 = (i & 15) * 4;
    size_t src = (size_t)(k * cB + b) * 256 + h * 64 + d4;
    uint2 kv = *(const uint2*)&Kb[src];
    uint2 vv = *(const uint2*)&Vb[src];
    *(uint2*)&KL[k * 72 + d4] = kv;
    const ushort_t* vvp = (const ushort_t*)&vv;
    #pragma unroll
    for (int t = 0; t < 4; ++t) VtL[(d4 + t) * 136 + k] = vvp[t];
  }
  if (tid < 128) tkL[tid] = tk[tid * cB + b];
  __syncthreads();
  const int pk = pad_k[b];
  const int pq = pad_q[b] * cHW;
  ushort_t* pRow = pL[w];
  const f32x4 z = {0.f, 0.f, 0.f, 0.f};

  for (int pr = 0; pr < 2; ++pr) {
    int qt = blockIdx.x * 16 + pr * 8 + w;
    if (qt >= 293) break;                       // wave-uniform
    const ushort_t* qrow =
        Qb + ((size_t)((qt * 16 + m15) * cB + b)) * 256 + h * 64 + quad * 8;
    short8 qa0 = *(const short8*)(qrow);
    short8 qa1 = *(const short8*)(qrow + 32);
    f32x4 s[8];
    #pragma unroll
    for (int nf = 0; nf < 8; ++nf) {
      const ushort_t* kp = KL + (nf * 16 + m15) * 72 + quad * 8;
      short8 b0 = *(const short8*)(kp);
      short8 b1 = *(const short8*)(kp + 32);
      s[nf] = __builtin_amdgcn_mfma_f32_16x16x32_bf16(qa0, b0, z, 0, 0, 0);
      s[nf] = __builtin_amdgcn_mfma_f32_16x16x32_bf16(qa1, b1, s[nf], 0, 0, 0);
    }
    int tqv[4], qok[4];
    #pragma unroll
    for (int i = 0; i < 4; ++i) {
      int qg = qt * 16 + quad * 4 + i;
      int sidx = (qg * 3579) >> 20;            // exact q/293 for q<14768
      tqv[i] = tq[sidx * cB + b];
      qok[i] = (qg < pq);
    }
    #pragma unroll
    for (int nf = 0; nf < 8; ++nf) {
      int kidx = nf * 16 + m15;
      int tkc = tkL[kidx];
      bool kok = (kidx < pk);
      #pragma unroll
      for (int i = 0; i < 4; ++i) {
        bool ok = kok && qok[i] && (tkc <= tqv[i]);
        s[nf][i] = ok ? s[nf][i] * 0.125f : -1e9f;
      }
    }
    float mx[4], l[4];
    #pragma unroll
    for (int i = 0; i < 4; ++i) {
      float m = s[0][i];
      #pragma unroll
      for (int nf = 1; nf < 8; ++nf) m = fmaxf(m, s[nf][i]);
      #pragma unroll
      for (int off = 8; off >= 1; off >>= 1) m = fmaxf(m, __shfl_xor(m, off, 64));
      mx[i] = m;
    }
    #pragma unroll
    for (int i = 0; i < 4; ++i) l[i] = 0.f;
    #pragma unroll
    for (int nf = 0; nf < 8; ++nf)
      #pragma unroll
      for (int i = 0; i < 4; ++i) {
        float p = __expf(s[nf][i] - mx[i]);
        s[nf][i] = p;
        l[i] += p;
      }
    #pragma unroll
    for (int i = 0; i < 4; ++i) {
      float t = l[i];
      #pragma unroll
      for (int off = 8; off >= 1; off >>= 1) t += __shfl_xor(t, off, 64);
      l[i] = 1.0f / t;
    }
    #pragma unroll
    for (int nf = 0; nf < 8; ++nf)
      #pragma unroll
      for (int i = 0; i < 4; ++i)
        pRow[(quad * 4 + i) * 136 + nf * 16 + m15] = f2bf(s[nf][i]);
    f32x4 o[4];
    #pragma unroll
    for (int nf = 0; nf < 4; ++nf) o[nf] = z;
    #pragma unroll
    for (int kc = 0; kc < 4; ++kc) {
      short8 pa = *(const short8*)(pRow + m15 * 136 + kc * 32 + quad * 8);
      #pragma unroll
      for (int nf = 0; nf < 4; ++nf) {
        short8 vb = *(const short8*)(VtL + (nf * 16 + m15) * 136 + kc * 32 + quad * 8);
        o[nf] = __builtin_amdgcn_mfma_f32_16x16x32_bf16(pa, vb, o[nf], 0, 0, 0);
      }
    }
    #pragma unroll
    for (int nf = 0; nf < 4; ++nf) {
      int c = h * 64 + nf * 16 + m15;
      size_t base = ((size_t)(c >> 5)) * 64 + ((c >> 3) & 3) * 16 + b;
      int cj = c & 7;
      #pragma unroll
      for (int i = 0; i < 4; ++i) {
        int qg = qt * 16 + quad * 4 + i;
        aout[(((size_t)qg * 8) * 64 + base) * 8 + cj] = f2bf(o[nf][i] * l[i]);
      }
    }
  }
}

// ============ MFMA table/hand heads + gx heads (merged) ============
__global__ __launch_bounds__(256, 4) void k_thg(
    const ushort_t* __restrict__ x2, const ushort_t* __restrict__ tws,
    const float* __restrict__ tb, const ushort_t* __restrict__ hws,
    const float* __restrict__ hb,
    const float* __restrict__ mw, const float* __restrict__ mbi,
    const float* __restrict__ sw, const float* __restrict__ sbi,
    const float* __restrict__ cw, const float* __restrict__ cbi,
    float* __restrict__ out)
{
  __shared__ ushort_t aT[64 * 264];
  const int NTH = cNN / 64;                    // 1172
  const int tid = threadIdx.x;
  if ((int)blockIdx.x >= NTH) {
    // ---- gx heads
    int sb = blockIdx.x - NTH;                 // s*16 + b
    int s = sb >> 4, b = sb & 15;
    float* rowL = (float*)aT;
    const ushort_t* row = x2 + ((size_t)(s * cHW + 292) * cB + b) * cC;
    rowL[tid] = bf2f(row[tid]);
    __syncthreads();
    int j = tid;
    if (j < 100) {
      const float* W;
      const float* Bi;
      int jj, M;
      size_t off;
      if (j < 20)      { W = mw; Bi = mbi; jj = j;      M = 20; off = 0;     }
      else if (j < 84) { W = sw; Bi = sbi; jj = j - 20; M = 64; off = 5120;  }
      else             { W = cw; Bi = cbi; jj = j - 84; M = 16; off = 21504; }
      float acc = Bi[jj];
      for (int c = 0; c < 256; ++c) acc = fmaf(rowL[c], W[c * M + jj], acc);
      out[off + (size_t)sb * M + jj] = acc;
    }
    return;
  }
  const int lane = tid & 63, w = tid >> 6;
  const int m15 = lane & 15, quad = lane >> 4;
  const int row0 = blockIdx.x * 64;
  #pragma unroll
  for (int it = 0; it < 8; ++it) {
    int f = tid + it * 256;
    int row = f >> 5, cb = f & 31;
    *(uint4*)&aT[row * 264 + cb * 8] =
        *(const uint4*)&x2[(size_t)(row0 + row) * 256 + cb * 8];
  }
  __syncthreads();
  const f32x4 z = {0.f, 0.f, 0.f, 0.f};
  f32x4 ct[2], ch[2];
  ct[0] = ct[1] = ch[0] = ch[1] = z;
  const ushort_t* arow = aT + (w * 16 + m15) * 264 + quad * 8;
  #pragma unroll
  for (int kc = 0; kc < 8; ++kc) {
    short8 a = *(const short8*)(arow + kc * 32);
    #pragma unroll
    for (int nb = 0; nb < 2; ++nb) {
      short8 bt_ = *(const short8*)(tws + (((size_t)(kc * 2 + nb)) * 64 + lane) * 8);
      short8 bh_ = *(const short8*)(hws + (((size_t)(kc * 2 + nb)) * 64 + lane) * 8);
      ct[nb] = __builtin_amdgcn_mfma_f32_16x16x32_bf16(a, bt_, ct[nb], 0, 0, 0);
      ch[nb] = __builtin_amdgcn_mfma_f32_16x16x32_bf16(a, bh_, ch[nb], 0, 0, 0);
    }
  }
  #pragma unroll
  for (int nb = 0; nb < 2; ++nb) {
    int j = nb * 16 + m15;
    float tbias = tb[j], hbias = hb[j];
    int uh = j >> 3, uw = (j >> 1) & 3, uc = j & 1;
    #pragma unroll
    for (int i = 0; i < 4; ++i) {
      int rg = row0 + w * 16 + quad * 4 + i;
      int b = rg & 15, q = rg >> 4;
      int s = (q * 3579) >> 20;          // exact q/293 for q<14768
      int hw = q - s * cHW;
      if (hw < 256) {
        int th = hw >> 4, twi = hw & 15;
        size_t idx = TX_OFF +
            ((((size_t)(s * cB + b)) * 2 + uc) * 64 + (th * 4 + uh)) * 64 + (twi * 4 + uw);
        out[idx] = ct[nb][i] + tbias;
      } else if (hw < 292) {
        int h2 = hw - 256;
        int hh = h2 / 6, ww = h2 % 6;
        size_t idx = HX_OFF +
            ((((size_t)(s * cB + b)) * 2 + uc) * 24 + (hh * 4 + uh)) * 24 + (ww * 4 + uw);
        out[idx] = ch[nb][i] + hbias;
      }
    }
  }
}

extern "C" void kernel_launch(void* const* d_in, const int* in_sizes, int n_in,
                              void* d_out, int out_size, void* d_ws, size_t ws_size,
                              hipStream_t stream)
{
  const int*   tq       = (const int*)d_in[0];
  const int*   pad_q    = (const int*)d_in[1];
  const float* xk       = (const float*)d_in[2];
  const int*   tk       = (const int*)d_in[3];
  const int*   pad_k    = (const int*)d_in[4];
  const float* spatial  = (const float*)d_in[8];
  const float* temporal = (const float*)d_in[9];
  const float* ln1_g    = (const float*)d_in[10];
  const float* ln1_b    = (const float*)d_in[11];
  const float* wq       = (const float*)d_in[12];
  const float* bq       = (const float*)d_in[13];
  const float* wk       = (const float*)d_in[14];
  const float* bk       = (const float*)d_in[15];
  const float* wv       = (const float*)d_in[16];
  const float* bv       = (const float*)d_in[17];
  const float* wo       = (const float*)d_in[18];
  const float* bo       = (const float*)d_in[19];
  const float* ln2_g    = (const float*)d_in[20];
  const float* ln2_b    = (const float*)d_in[21];
  const float* w1       = (const float*)d_in[22];
  const float* b1       = (const float*)d_in[23];
  const float* w2       = (const float*)d_in[24];
  const float* b2       = (const float*)d_in[25];
  const float* table_w  = (const float*)d_in[26];
  const float* table_b  = (const float*)d_in[27];
  const float* hand_w   = (const float*)d_in[28];
  const float* hand_b   = (const float*)d_in[29];
  const float* mode_w   = (const float*)d_in[30];
  const float* mode_b   = (const float*)d_in[31];
  const float* shape_w  = (const float*)d_in[32];
  const float* shape_b  = (const float*)d_in[33];
  const float* color_w  = (const float*)d_in[34];
  const float* color_b  = (const float*)d_in[35];
  float* out = (float*)d_out;

  char* ws = (char*)d_ws;
  const size_t NB2 = (size_t)cNN * cC * sizeof(ushort_t);      // 38,404,096
  ushort_t* buf1 = (ushort_t*)ws;                              // a_swz -> x stash
  ushort_t* buf2 = (ushort_t*)(ws + NB2);                      // Q -> x2
  char* p = ws + 2 * NB2;
  ushort_t* Kb  = (ushort_t*)p;  p += (size_t)cLK * cB * 256 * 2;
  ushort_t* Vb  = (ushort_t*)p;  p += (size_t)cLK * cB * 256 * 2;
  ushort_t* xkb = (ushort_t*)p;  p += (size_t)cLK * cB * 256 * 2;
  ushort_t* wqs = (ushort_t*)p;  p += 256 * 256 * 2;
  ushort_t* wks = (ushort_t*)p;  p += 256 * 256 * 2;
  ushort_t* wvs = (ushort_t*)p;  p += 256 * 256 * 2;
  ushort_t* wos = (ushort_t*)p;  p += 256 * 256 * 2;
  ushort_t* w1s = (ushort_t*)p;  p += 256 * 1024 * 2;
  ushort_t* w2s = (ushort_t*)p;  p += 1024 * 256 * 2;
  ushort_t* tws = (ushort_t*)p;  p += 256 * 32 * 2;
  ushort_t* hws = (ushort_t*)p;  p += 256 * 32 * 2;

  k_prep<<<904, 256, 0, stream>>>(xk, xkb, wq, wqs, wk, wks, wv, wvs,
                                  wo, wos, w1, w1s, w2, w2s,
                                  table_w, tws, hand_w, hws);
  k_qnpkv<<<cNN / 64 + 64, 256, 0, stream>>>(tq, spatial, temporal, ln1_g, ln1_b,
                                             wqs, bq, buf2, xkb, wks, wvs,
                                             bk, bv, Kb, Vb);
  k_attn<<<dim3(19, cH, cB), 512, 0, stream>>>(buf2, Kb, Vb, tq, tk,
                                               pad_q, pad_k, buf1);
  k_woffn<<<cNN / 64, 512, 0, stream>>>(buf1, wos, bo, tq, spatial, temporal,
                                        ln2_g, ln2_b, w1s, b1, w2s, b2,
                                        buf1, buf2);
  k_thg<<<cNN / 64 + cS * cB, 256, 0, stream>>>(buf2, tws, table_b, hws, hand_b,
                                                mode_w, mode_b, shape_w, shape_b,
                                                color_w, color_b, out);
}